// Round 8
// baseline (402.619 us; speedup 1.0000x reference)
//
#include <hip/hip_runtime.h>
#include <hip/hip_bf16.h>

// CSMultiHeadAttention. B=8, S=3072 (3x1024), E=512, H=8, d=64.
// fp32 I/O, bf16 workspace, fp32 MFMA accumulate.
// R6/R7 changes (attn is LDS-pipe-bound: every wave re-reads the whole shared
// K/V tile -> 8x amplification at 8 waves):
//  - attn: 64 q/wave (nt=4), 4-wave blocks -> K/V LDS bytes per q halved
//  - K/V double-buffered + async prefetch -> 1 barrier/tile, load latency
//    hidden under compute (vmcnt(0) drain lands at the consuming barrier)
//  - denominators: per-lane VALU partials + 2 end shuffles (kills ones-MFMA,
//    -16 VGPR); softmax interleaved per-mt to keep sacc transient
//  - conv_x/conv_w merged into one launch
//  - R7: fix macro/braced-initializer compile error (hoisted zero4 constant)
// MFMA 16x16x32 bf16. A/B frag: [m|n = lane&15][k = (lane>>4)*8 + j].
// C/D: col = lane&15, row = (lane>>4)*4 + reg.
// GEMM LDS tiles XOR-swizzled (block kb ^ (row&7)): free 2-way banks AND
// matches global_load_lds lane-contiguous destination.

typedef __attribute__((ext_vector_type(8))) short short8v;     // 8 bf16 (4 VGPR)
typedef __attribute__((ext_vector_type(4))) float float4v;
typedef __attribute__((ext_vector_type(4))) unsigned short ushort4v;
typedef __attribute__((ext_vector_type(4))) unsigned int uint4v;
typedef __attribute__((ext_vector_type(2))) unsigned int uint2v;

#define CHUNKS 3
#define BATCH 8
#define SEQ 3072
#define EMB 512
#define NH 8
#define HD 64
#define NCK 1024
#define MTOT (BATCH*SEQ)                      // 24576
#define QKV_ELEMS (CHUNKS*BATCH*NH*NCK*HD)    // 12582912 (== x elem count)
#define WELEMS (CHUNKS*EMB*EMB)               // 786432 per weight tensor
// 1/sqrt(512) * log2(e): softmax exp folded to exp2
#define QSCALE 0.06375872465f

__device__ __forceinline__ unsigned short f2b(float f) {
  union { float f; unsigned int i; } x; x.f = f;
  unsigned int r = x.i + 0x7FFFu + ((x.i >> 16) & 1u);  // RNE
  return (unsigned short)(r >> 16);
}
// pack two fp32 -> two bf16 (round-half-up) in 3 VALU via v_perm
__device__ __forceinline__ unsigned int pack2r(float a, float b) {
  union { float f; unsigned int u; } xa, xb; xa.f = a; xb.f = b;
  return __builtin_amdgcn_perm(xb.u + 0x8000u, xa.u + 0x8000u, 0x07060302u);
}
__device__ __forceinline__ void gld_lds16(const unsigned short* g, unsigned short* l) {
  __builtin_amdgcn_global_load_lds(
      (const __attribute__((address_space(1))) unsigned int*)g,
      (__attribute__((address_space(3))) unsigned int*)l, 16, 0, 0);
}
#define MFMA(a, b, c) __builtin_amdgcn_mfma_f32_16x16x32_bf16(a, b, c, 0, 0, 0)

// ---------------- fp32 -> bf16 conversion (x + 4 weight tensors, one launch) --
#define XBLK (QKV_ELEMS / 2048)   // 6144
#define WBLK (WELEMS / 2048)      // 384
__global__ __launch_bounds__(256) void conv_all(
    const float* __restrict__ x,
    const float* __restrict__ w0, const float* __restrict__ w1,
    const float* __restrict__ w2, const float* __restrict__ w3,
    unsigned short* __restrict__ xbf, unsigned short* __restrict__ Wb)
{
  const int bid = blockIdx.x;
  const float* src;
  unsigned short* dst;
  size_t i;
  if (bid < XBLK) {
    src = x; dst = xbf;
    i = ((size_t)bid * 256 + threadIdx.x) * 8;
  } else {
    const int z = (bid - XBLK) / WBLK;
    const int ob = (bid - XBLK) % WBLK;
    src = (z == 0) ? w0 : (z == 1) ? w1 : (z == 2) ? w2 : w3;
    dst = Wb + (size_t)z * WELEMS;
    i = ((size_t)ob * 256 + threadIdx.x) * 8;
  }
  float4 a = *(const float4*)&src[i];
  float4 b = *(const float4*)&src[i + 4];
  uint4v p;
  p[0] = pack2r(a.x, a.y); p[1] = pack2r(a.z, a.w);
  p[2] = pack2r(b.x, b.y); p[3] = pack2r(b.z, b.w);
  *(uint4v*)&dst[i] = p;
}

// ---------------- QKV projection (unchanged from R5) ----------------
__global__ __launch_bounds__(256) void qkv_gemm(
    const unsigned short* __restrict__ xb, const unsigned short* __restrict__ Wb,
    const float* __restrict__ bq, const float* __restrict__ bk,
    const float* __restrict__ bv,
    unsigned short* __restrict__ qt, unsigned short* __restrict__ kt,
    unsigned short* __restrict__ vt)
{
  const int tid = threadIdx.x;
  const int w = tid >> 6, l = tid & 63;
  const int ln = l & 15, qu = l >> 4;
  const int sr = l >> 3, kbl = l & 7;
  const int row0 = blockIdx.x * 128;
  const int col0 = blockIdx.y * 128;
  const int z = blockIdx.z;
  const int bglob = row0 / SEQ;
  const int c = (row0 % SEQ) / NCK;
  const int n0 = row0 % NCK;
  const unsigned short* W = Wb + (size_t)z * WELEMS + c * EMB * EMB;
  const float* bias = (z == 0 ? bq : (z == 1 ? bk : bv)) + c * EMB;
  const float oscale = (z == 0) ? QSCALE : 1.0f;

  __shared__ unsigned short As[128 * 64];   // x-tile, swizzled
  __shared__ unsigned short Bs[128 * 64];   // W-tile, swizzled

  const int xo = (w & 1) * 64, fo = (w >> 1) * 64;

  float4v acc[4][4];
#pragma unroll
  for (int i = 0; i < 4; ++i)
#pragma unroll
    for (int j = 0; j < 4; ++j) acc[i][j] = (float4v){0.f, 0.f, 0.f, 0.f};

  for (int k0 = 0; k0 < EMB; k0 += 64) {
    __syncthreads();
#pragma unroll
    for (int s = 0; s < 4; ++s) {
      int rbase = w * 32 + s * 8;
      int r = rbase + sr;                    // per-lane global row
      int kb_g = kbl ^ sr;                   // swizzled k-block
      gld_lds16(&xb[(size_t)(row0 + r) * EMB + k0 + kb_g * 8], &As[rbase * 64]);
      gld_lds16(&W [(size_t)(col0 + r) * EMB + k0 + kb_g * 8], &Bs[rbase * 64]);
    }
    __syncthreads();
#pragma unroll
    for (int ks = 0; ks < 2; ++ks) {
      short8v xf[4], wf[4];
#pragma unroll
      for (int i = 0; i < 4; ++i) {
        int rx = xo + 16 * i + ln;
        xf[i] = *(const short8v*)&As[rx * 64 + (((ks * 4 + qu) ^ (rx & 7)) * 8)];
        int rw = fo + 16 * i + ln;
        wf[i] = *(const short8v*)&Bs[rw * 64 + (((ks * 4 + qu) ^ (rw & 7)) * 8)];
      }
      if (z <= 1) {
#pragma unroll
        for (int i = 0; i < 4; ++i)
#pragma unroll
          for (int j = 0; j < 4; ++j) acc[i][j] = MFMA(wf[j], xf[i], acc[i][j]);
      } else {
#pragma unroll
        for (int i = 0; i < 4; ++i)
#pragma unroll
          for (int j = 0; j < 4; ++j) acc[i][j] = MFMA(xf[i], wf[j], acc[i][j]);
      }
    }
  }

  if (z <= 1) {
    unsigned short* outp = (z == 0) ? qt : kt;
#pragma unroll
    for (int j = 0; j < 4; ++j) {            // f (M side)
      int f0 = col0 + fo + 16 * j + 4 * qu;  // + r
      float4 b4 = *(const float4*)&bias[f0];
      int hh = f0 >> 6, dd0 = f0 & 63;
      size_t base = ((size_t)((c * 8 + bglob) * 8 + hh)) << 16;
#pragma unroll
      for (int i = 0; i < 4; ++i) {          // token (N side)
        int n = n0 + xo + 16 * i + ln;
        ushort4v p;
#pragma unroll
        for (int r = 0; r < 4; ++r)
          p[r] = f2b((acc[i][j][r] + ((const float*)&b4)[r]) * oscale);
        *(ushort4v*)&outp[base + (size_t)n * 64 + dd0] = p;
      }
    }
  } else {
#pragma unroll
    for (int i = 0; i < 4; ++i) {            // token (M side)
      int nn0 = n0 + xo + 16 * i + 4 * qu;   // + r
#pragma unroll
      for (int j = 0; j < 4; ++j) {          // f (N side)
        int f = col0 + fo + 16 * j + ln;
        int hh = f >> 6, dd = f & 63;
        float bvv = bias[f];
        size_t base = ((size_t)((c * 8 + bglob) * 8 + hh)) << 16;
        ushort4v p;
#pragma unroll
        for (int r = 0; r < 4; ++r) p[r] = f2b(acc[i][j][r] + bvv);
        *(ushort4v*)&vt[base + (size_t)dd * 1024 + nn0] = p;
      }
    }
  }
}

// ---------------- Attention (flash, MFMA) ----------------
// 256 threads / 4 waves / 64 q per wave (256 q rows per block).
// Grid bid = qb*192 + head -> same-head blocks on one XCD (bid%8 const).
// K/V double-buffered: prefetch tile t+1 right after the barrier that drains
// tile t; one barrier per tile. Per tile: per-mt S MFMAs -> exp2+pack -> Ps;
// per 32-key half PV (O^T += V^T P^T). Denominator: per-lane VALU partials
// (all 4 sacc regs share q=col=lane&15), 2 shfl_xor at the end.
__global__ __launch_bounds__(256, 3) void attn_kernel(
    const unsigned short* __restrict__ qt,
    const unsigned short* __restrict__ kt,
    const unsigned short* __restrict__ vt,
    unsigned short* __restrict__ attnb)
{
  const int tid = threadIdx.x;
  const int w = tid >> 6, l = tid & 63;
  const int ln = l & 15, qu = l >> 4;
  const int sr = l >> 3, kbl = l & 7;
  const int bid = blockIdx.x;
  const int hd = bid % 192;                  // (co,b,h)
  const int q0 = (bid / 192) * 256;
  const int co = hd >> 6;
  const int b  = (hd >> 3) & 7;
  const int h  = hd & 7;
  const int cq = (co + 1) % 3, ckv = (co + 2) % 3;
  const unsigned short* Qg = qt + ((size_t)((cq  * 8 + b) * 8 + h) << 16);
  const unsigned short* Kg = kt + ((size_t)((ckv * 8 + b) * 8 + h) << 16);
  const unsigned short* Vg = vt + ((size_t)((ckv * 8 + b) * 8 + h) << 16);

  __shared__ unsigned short Ks[2][64 * 64];  // [key][d] swizzled, 2x8KB
  __shared__ unsigned short Vs[2][64 * 64];  // [d][key] swizzled, 2x8KB
  __shared__ unsigned short Ps[4][64 * 36];  // per-wave [q][32-key half], 18.4KB

  const float4v zero4 = {0.f, 0.f, 0.f, 0.f};

  // Q B-frags: q = q0 + w*64 + nt*16 + ln; k = ks*32 + qu*8 + j
  short8v qf[4][2];
#pragma unroll
  for (int nt = 0; nt < 4; ++nt)
#pragma unroll
    for (int ks = 0; ks < 2; ++ks)
      qf[nt][ks] = *(const short8v*)&Qg[(size_t)(q0 + w * 64 + nt * 16 + ln) * 64 + ks * 32 + qu * 8];

  float4v acc_o[4][4];
#pragma unroll
  for (int i = 0; i < 4; ++i)
#pragma unroll
    for (int j = 0; j < 4; ++j) acc_o[i][j] = zero4;
  float lsum[4] = {0.f, 0.f, 0.f, 0.f};

  // stage tile (64 keys) into buffer buf: 4 waves x 2 issues x 8 rows
#define STAGE(buf, kt0_)                                                        \
  {                                                                             \
    _Pragma("unroll")                                                           \
    for (int s = 0; s < 2; ++s) {                                               \
      int rbase = w * 16 + s * 8;                                               \
      int r = rbase + sr;                                                       \
      gld_lds16(&Kg[(size_t)((kt0_) + r) * 64 + ((kbl ^ sr) * 8)],              \
                &Ks[buf][rbase * 64]);                                          \
      gld_lds16(&Vg[(size_t)r * 1024 + (kt0_) + ((kbl ^ sr) * 8)],              \
                &Vs[buf][rbase * 64]);                                          \
    }                                                                           \
  }

  STAGE(0, 0)
  for (int t = 0; t < 16; ++t) {
    const int cur = t & 1;
    __syncthreads();                         // drains prefetch of tile t
    if (t < 15) STAGE(cur ^ 1, (t + 1) * 64)

#pragma unroll
    for (int half = 0; half < 2; ++half) {
      // S-phase + softmax for the two 16-key groups of this half
#pragma unroll
      for (int mh = 0; mh < 2; ++mh) {
        int mt = half * 2 + mh;
        int key = 16 * mt + ln;
        short8v kf0 = *(const short8v*)&Ks[cur][key * 64 + ((qu ^ (key & 7)) * 8)];
        short8v kf1 = *(const short8v*)&Ks[cur][key * 64 + (((4 + qu) ^ (key & 7)) * 8)];
#pragma unroll
        for (int nt = 0; nt < 4; ++nt) {
          float4v s4 = MFMA(kf0, qf[nt][0], zero4);
          s4 = MFMA(kf1, qf[nt][1], s4);
          float e0 = __builtin_amdgcn_exp2f(s4[0]);
          float e1 = __builtin_amdgcn_exp2f(s4[1]);
          float e2 = __builtin_amdgcn_exp2f(s4[2]);
          float e3 = __builtin_amdgcn_exp2f(s4[3]);
          lsum[nt] += (e0 + e1) + (e2 + e3);
          uint2v u;
          u[0] = pack2r(e0, e1);
          u[1] = pack2r(e2, e3);
          *(uint2v*)&Ps[w][(nt * 16 + ln) * 36 + 16 * mh + 4 * qu] = u;
        }
      }
      // PV-phase for this half: O^T[d][q] += V^T · P^T
      short8v pf[4];
#pragma unroll
      for (int nt = 0; nt < 4; ++nt)
        pf[nt] = *(const short8v*)&Ps[w][(nt * 16 + ln) * 36 + qu * 8];
#pragma unroll
      for (int mtv = 0; mtv < 4; ++mtv) {
        int dd = 16 * mtv + ln;
        short8v vf = *(const short8v*)&Vs[cur][dd * 64 + (((half * 4 + qu) ^ (dd & 7)) * 8)];
#pragma unroll
        for (int nt = 0; nt < 4; ++nt)
          acc_o[mtv][nt] = MFMA(vf, pf[nt], acc_o[mtv][nt]);
      }
    }
  }
#undef STAGE

  float inv[4];
#pragma unroll
  for (int nt = 0; nt < 4; ++nt) {
    float tt = lsum[nt];
    tt += __shfl_xor(tt, 16);
    tt += __shfl_xor(tt, 32);
    inv[nt] = 1.0f / tt;
  }
  unsigned short* Og = attnb + (size_t)((co * 8 + b)) * NCK * EMB + h * HD;
#pragma unroll
  for (int mtv = 0; mtv < 4; ++mtv) {
    int dd0 = 16 * mtv + 4 * qu;
#pragma unroll
    for (int nt = 0; nt < 4; ++nt) {
      int q_glob = q0 + w * 64 + nt * 16 + ln;
      ushort4v p;
#pragma unroll
      for (int r = 0; r < 4; ++r) p[r] = f2b(acc_o[mtv][nt][r] * inv[nt]);
      *(ushort4v*)&Og[(size_t)q_glob * EMB + dd0] = p;
    }
  }
}

// ---------------- Output projection (unchanged from R5) ----------------
__global__ __launch_bounds__(256) void proj_gemm(
    const unsigned short* __restrict__ attnb,
    const unsigned short* __restrict__ Wpb, const float* __restrict__ bp,
    float* __restrict__ out)
{
  const int tid = threadIdx.x;
  const int w = tid >> 6, l = tid & 63;
  const int ln = l & 15, qu = l >> 4;
  const int sr = l >> 3, kbl = l & 7;
  const int row0 = blockIdx.x * 128;          // [c][b][n] rows
  const int col0 = blockIdx.y * 128;
  const int c = row0 >> 13;
  const int bglob = (row0 >> 10) & 7;
  const int n0 = row0 & 1023;
  const unsigned short* W = Wpb + c * EMB * EMB;
  const float* bias = bp + c * EMB;

  __shared__ unsigned short As[128 * 64];
  __shared__ unsigned short Bs[128 * 64];

  const int xo = (w & 1) * 64, fo = (w >> 1) * 64;

  float4v acc[4][4];
#pragma unroll
  for (int i = 0; i < 4; ++i)
#pragma unroll
    for (int j = 0; j < 4; ++j) acc[i][j] = (float4v){0.f, 0.f, 0.f, 0.f};

  for (int k0 = 0; k0 < EMB; k0 += 64) {
    __syncthreads();
#pragma unroll
    for (int s = 0; s < 4; ++s) {
      int rbase = w * 32 + s * 8;
      int r = rbase + sr;
      int kb_g = kbl ^ sr;
      gld_lds16(&attnb[(size_t)(row0 + r) * EMB + k0 + kb_g * 8], &As[rbase * 64]);
      gld_lds16(&W    [(size_t)(col0 + r) * EMB + k0 + kb_g * 8], &Bs[rbase * 64]);
    }
    __syncthreads();
#pragma unroll
    for (int ks = 0; ks < 2; ++ks) {
      short8v xf[4], wf[4];
#pragma unroll
      for (int i = 0; i < 4; ++i) {
        int rx = xo + 16 * i + ln;
        xf[i] = *(const short8v*)&As[rx * 64 + (((ks * 4 + qu) ^ (rx & 7)) * 8)];
        int rw = fo + 16 * i + ln;
        wf[i] = *(const short8v*)&Bs[rw * 64 + (((ks * 4 + qu) ^ (rw & 7)) * 8)];
      }
#pragma unroll
      for (int i = 0; i < 4; ++i)
#pragma unroll
        for (int j = 0; j < 4; ++j) acc[i][j] = MFMA(wf[j], xf[i], acc[i][j]);
    }
  }

#pragma unroll
  for (int j = 0; j < 4; ++j) {              // f (M side)
    int f0 = col0 + fo + 16 * j + 4 * qu;    // + r
    float4 b4 = *(const float4*)&bias[f0];
#pragma unroll
    for (int i = 0; i < 4; ++i) {            // token (N side)
      int srow = bglob * SEQ + c * NCK + n0 + xo + 16 * i + ln;
      float4 o;
      o.x = acc[i][j][0] + b4.x;
      o.y = acc[i][j][1] + b4.y;
      o.z = acc[i][j][2] + b4.z;
      o.w = acc[i][j][3] + b4.w;
      *(float4*)&out[(size_t)srow * EMB + f0] = o;
    }
  }
}

extern "C" void kernel_launch(void* const* d_in, const int* in_sizes, int n_in,
                              void* d_out, int out_size, void* d_ws, size_t ws_size,
                              hipStream_t stream) {
  (void)in_sizes; (void)n_in; (void)out_size; (void)ws_size;
  const float* x  = (const float*)d_in[0];
  const float* Wq = (const float*)d_in[1];
  const float* bq = (const float*)d_in[2];
  const float* Wk = (const float*)d_in[3];
  const float* bk = (const float*)d_in[4];
  const float* Wv = (const float*)d_in[5];
  const float* bv = (const float*)d_in[6];
  const float* Wp = (const float*)d_in[7];
  const float* bp = (const float*)d_in[8];
  float* out = (float*)d_out;

  // workspace layout (bf16 elems): [Wb 4*WELEMS][qt][kt][vt][attn(=x_bf)]
  // = 6.3 MB + 4*25.2 MB = 107 MB. x_bf aliases the attn slot: x_bf is only
  // read by qkv_gemm, which completes before attn_kernel writes attnb.
  unsigned short* Wb   = (unsigned short*)d_ws;
  unsigned short* qt   = Wb + 4 * (size_t)WELEMS;
  unsigned short* kt   = qt + QKV_ELEMS;
  unsigned short* vt   = kt + QKV_ELEMS;
  unsigned short* attn = vt + QKV_ELEMS;
  unsigned short* xbf  = attn;  // alias (see above)

  conv_all<<<XBLK + 4 * WBLK, 256, 0, stream>>>(x, Wq, Wk, Wv, Wp, xbf, Wb);
  qkv_gemm<<<dim3(MTOT / 128, EMB / 128, 3), 256, 0, stream>>>(
      xbf, Wb, bq, bk, bv, qt, kt, vt);
  attn_kernel<<<(NCK / 256) * CHUNKS * BATCH * NH, 256, 0, stream>>>(qt, kt, vt, attn);
  proj_gemm<<<dim3(MTOT / 128, EMB / 128), 256, 0, stream>>>(attn, Wb + 3 * (size_t)WELEMS, bp, out);
}

// Round 9
// 324.128 us; speedup vs baseline: 1.2422x; 1.2422x over previous
//
#include <hip/hip_runtime.h>
#include <hip/hip_bf16.h>

// CSMultiHeadAttention. B=8, S=3072 (3x1024), E=512, H=8, d=64.
// fp32 I/O, bf16 workspace, fp32 MFMA accumulate.
// R8 change: R7's __launch_bounds__(256,3) drove the allocator to an 84-VGPR
// budget (6 waves/EU target) -> acc_o spilled to scratch -> 360MB/way HBM
// round-trip (WRITE 383MB, 199us, HBM-bound at 51%). Fix: plain
// __launch_bounds__(256); kernel needs ~150 VGPR -> 3 waves/EU, which matches
// the LDS limit (50.4KB -> 3 blocks/CU) anyway.
// Attn structure (R6 theory, now actually testable): 64 q/wave, 4-wave blocks,
// K/V double-buffered async prefetch, 1 barrier/tile, VALU denominators.
// MFMA 16x16x32 bf16. A/B frag: [m|n = lane&15][k = (lane>>4)*8 + j].
// C/D: col = lane&15, row = (lane>>4)*4 + reg.
// GEMM LDS tiles XOR-swizzled (block kb ^ (row&7)): free 2-way banks AND
// matches global_load_lds lane-contiguous destination.

typedef __attribute__((ext_vector_type(8))) short short8v;     // 8 bf16 (4 VGPR)
typedef __attribute__((ext_vector_type(4))) float float4v;
typedef __attribute__((ext_vector_type(4))) unsigned short ushort4v;
typedef __attribute__((ext_vector_type(4))) unsigned int uint4v;
typedef __attribute__((ext_vector_type(2))) unsigned int uint2v;

#define CHUNKS 3
#define BATCH 8
#define SEQ 3072
#define EMB 512
#define NH 8
#define HD 64
#define NCK 1024
#define MTOT (BATCH*SEQ)                      // 24576
#define QKV_ELEMS (CHUNKS*BATCH*NH*NCK*HD)    // 12582912 (== x elem count)
#define WELEMS (CHUNKS*EMB*EMB)               // 786432 per weight tensor
// 1/sqrt(512) * log2(e): softmax exp folded to exp2
#define QSCALE 0.06375872465f

__device__ __forceinline__ unsigned short f2b(float f) {
  union { float f; unsigned int i; } x; x.f = f;
  unsigned int r = x.i + 0x7FFFu + ((x.i >> 16) & 1u);  // RNE
  return (unsigned short)(r >> 16);
}
// pack two fp32 -> two bf16 (round-half-up) in 3 VALU via v_perm
__device__ __forceinline__ unsigned int pack2r(float a, float b) {
  union { float f; unsigned int u; } xa, xb; xa.f = a; xb.f = b;
  return __builtin_amdgcn_perm(xb.u + 0x8000u, xa.u + 0x8000u, 0x07060302u);
}
__device__ __forceinline__ void gld_lds16(const unsigned short* g, unsigned short* l) {
  __builtin_amdgcn_global_load_lds(
      (const __attribute__((address_space(1))) unsigned int*)g,
      (__attribute__((address_space(3))) unsigned int*)l, 16, 0, 0);
}
#define MFMA(a, b, c) __builtin_amdgcn_mfma_f32_16x16x32_bf16(a, b, c, 0, 0, 0)

// ---------------- fp32 -> bf16 conversion (x + 4 weight tensors, one launch) --
#define XBLK (QKV_ELEMS / 2048)   // 6144
#define WBLK (WELEMS / 2048)      // 384
__global__ __launch_bounds__(256) void conv_all(
    const float* __restrict__ x,
    const float* __restrict__ w0, const float* __restrict__ w1,
    const float* __restrict__ w2, const float* __restrict__ w3,
    unsigned short* __restrict__ xbf, unsigned short* __restrict__ Wb)
{
  const int bid = blockIdx.x;
  const float* src;
  unsigned short* dst;
  size_t i;
  if (bid < XBLK) {
    src = x; dst = xbf;
    i = ((size_t)bid * 256 + threadIdx.x) * 8;
  } else {
    const int z = (bid - XBLK) / WBLK;
    const int ob = (bid - XBLK) % WBLK;
    src = (z == 0) ? w0 : (z == 1) ? w1 : (z == 2) ? w2 : w3;
    dst = Wb + (size_t)z * WELEMS;
    i = ((size_t)ob * 256 + threadIdx.x) * 8;
  }
  float4 a = *(const float4*)&src[i];
  float4 b = *(const float4*)&src[i + 4];
  uint4v p;
  p[0] = pack2r(a.x, a.y); p[1] = pack2r(a.z, a.w);
  p[2] = pack2r(b.x, b.y); p[3] = pack2r(b.z, b.w);
  *(uint4v*)&dst[i] = p;
}

// ---------------- QKV projection (unchanged) ----------------
__global__ __launch_bounds__(256) void qkv_gemm(
    const unsigned short* __restrict__ xb, const unsigned short* __restrict__ Wb,
    const float* __restrict__ bq, const float* __restrict__ bk,
    const float* __restrict__ bv,
    unsigned short* __restrict__ qt, unsigned short* __restrict__ kt,
    unsigned short* __restrict__ vt)
{
  const int tid = threadIdx.x;
  const int w = tid >> 6, l = tid & 63;
  const int ln = l & 15, qu = l >> 4;
  const int sr = l >> 3, kbl = l & 7;
  const int row0 = blockIdx.x * 128;
  const int col0 = blockIdx.y * 128;
  const int z = blockIdx.z;
  const int bglob = row0 / SEQ;
  const int c = (row0 % SEQ) / NCK;
  const int n0 = row0 % NCK;
  const unsigned short* W = Wb + (size_t)z * WELEMS + c * EMB * EMB;
  const float* bias = (z == 0 ? bq : (z == 1 ? bk : bv)) + c * EMB;
  const float oscale = (z == 0) ? QSCALE : 1.0f;

  __shared__ unsigned short As[128 * 64];   // x-tile, swizzled
  __shared__ unsigned short Bs[128 * 64];   // W-tile, swizzled

  const int xo = (w & 1) * 64, fo = (w >> 1) * 64;

  float4v acc[4][4];
#pragma unroll
  for (int i = 0; i < 4; ++i)
#pragma unroll
    for (int j = 0; j < 4; ++j) acc[i][j] = (float4v){0.f, 0.f, 0.f, 0.f};

  for (int k0 = 0; k0 < EMB; k0 += 64) {
    __syncthreads();
#pragma unroll
    for (int s = 0; s < 4; ++s) {
      int rbase = w * 32 + s * 8;
      int r = rbase + sr;                    // per-lane global row
      int kb_g = kbl ^ sr;                   // swizzled k-block
      gld_lds16(&xb[(size_t)(row0 + r) * EMB + k0 + kb_g * 8], &As[rbase * 64]);
      gld_lds16(&W [(size_t)(col0 + r) * EMB + k0 + kb_g * 8], &Bs[rbase * 64]);
    }
    __syncthreads();
#pragma unroll
    for (int ks = 0; ks < 2; ++ks) {
      short8v xf[4], wf[4];
#pragma unroll
      for (int i = 0; i < 4; ++i) {
        int rx = xo + 16 * i + ln;
        xf[i] = *(const short8v*)&As[rx * 64 + (((ks * 4 + qu) ^ (rx & 7)) * 8)];
        int rw = fo + 16 * i + ln;
        wf[i] = *(const short8v*)&Bs[rw * 64 + (((ks * 4 + qu) ^ (rw & 7)) * 8)];
      }
      if (z <= 1) {
#pragma unroll
        for (int i = 0; i < 4; ++i)
#pragma unroll
          for (int j = 0; j < 4; ++j) acc[i][j] = MFMA(wf[j], xf[i], acc[i][j]);
      } else {
#pragma unroll
        for (int i = 0; i < 4; ++i)
#pragma unroll
          for (int j = 0; j < 4; ++j) acc[i][j] = MFMA(xf[i], wf[j], acc[i][j]);
      }
    }
  }

  if (z <= 1) {
    unsigned short* outp = (z == 0) ? qt : kt;
#pragma unroll
    for (int j = 0; j < 4; ++j) {            // f (M side)
      int f0 = col0 + fo + 16 * j + 4 * qu;  // + r
      float4 b4 = *(const float4*)&bias[f0];
      int hh = f0 >> 6, dd0 = f0 & 63;
      size_t base = ((size_t)((c * 8 + bglob) * 8 + hh)) << 16;
#pragma unroll
      for (int i = 0; i < 4; ++i) {          // token (N side)
        int n = n0 + xo + 16 * i + ln;
        ushort4v p;
#pragma unroll
        for (int r = 0; r < 4; ++r)
          p[r] = f2b((acc[i][j][r] + ((const float*)&b4)[r]) * oscale);
        *(ushort4v*)&outp[base + (size_t)n * 64 + dd0] = p;
      }
    }
  } else {
#pragma unroll
    for (int i = 0; i < 4; ++i) {            // token (M side)
      int nn0 = n0 + xo + 16 * i + 4 * qu;   // + r
#pragma unroll
      for (int j = 0; j < 4; ++j) {          // f (N side)
        int f = col0 + fo + 16 * j + ln;
        int hh = f >> 6, dd = f & 63;
        float bvv = bias[f];
        size_t base = ((size_t)((c * 8 + bglob) * 8 + hh)) << 16;
        ushort4v p;
#pragma unroll
        for (int r = 0; r < 4; ++r) p[r] = f2b(acc[i][j][r] + bvv);
        *(ushort4v*)&vt[base + (size_t)dd * 1024 + nn0] = p;
      }
    }
  }
}

// ---------------- Attention (flash, MFMA) ----------------
// 256 threads / 4 waves / 64 q per wave (256 q rows per block).
// Grid bid = qb*192 + head -> same-head blocks on one XCD (bid%8 const).
// K/V double-buffered: prefetch tile t+1 right after the barrier that drains
// tile t; one barrier per tile. Per tile: per-mt S MFMAs -> exp2+pack -> Ps;
// per 32-key half PV (O^T += V^T P^T). Denominator: per-lane VALU partials
// (all 4 sacc regs share q=col=lane&15), 2 shfl_xor at the end.
// NOTE: plain __launch_bounds__(256) — a min-waves hint here caused an
// 84-VGPR cap + acc_o scratch spill (R7: 383MB writes, 199us).
__global__ __launch_bounds__(256) void attn_kernel(
    const unsigned short* __restrict__ qt,
    const unsigned short* __restrict__ kt,
    const unsigned short* __restrict__ vt,
    unsigned short* __restrict__ attnb)
{
  const int tid = threadIdx.x;
  const int w = tid >> 6, l = tid & 63;
  const int ln = l & 15, qu = l >> 4;
  const int sr = l >> 3, kbl = l & 7;
  const int bid = blockIdx.x;
  const int hd = bid % 192;                  // (co,b,h)
  const int q0 = (bid / 192) * 256;
  const int co = hd >> 6;
  const int b  = (hd >> 3) & 7;
  const int h  = hd & 7;
  const int cq = (co + 1) % 3, ckv = (co + 2) % 3;
  const unsigned short* Qg = qt + ((size_t)((cq  * 8 + b) * 8 + h) << 16);
  const unsigned short* Kg = kt + ((size_t)((ckv * 8 + b) * 8 + h) << 16);
  const unsigned short* Vg = vt + ((size_t)((ckv * 8 + b) * 8 + h) << 16);

  __shared__ unsigned short Ks[2][64 * 64];  // [key][d] swizzled, 2x8KB
  __shared__ unsigned short Vs[2][64 * 64];  // [d][key] swizzled, 2x8KB
  __shared__ unsigned short Ps[4][64 * 36];  // per-wave [q][32-key half], 18.4KB

  const float4v zero4 = {0.f, 0.f, 0.f, 0.f};

  // Q B-frags: q = q0 + w*64 + nt*16 + ln; k = ks*32 + qu*8 + j
  short8v qf[4][2];
#pragma unroll
  for (int nt = 0; nt < 4; ++nt)
#pragma unroll
    for (int ks = 0; ks < 2; ++ks)
      qf[nt][ks] = *(const short8v*)&Qg[(size_t)(q0 + w * 64 + nt * 16 + ln) * 64 + ks * 32 + qu * 8];

  float4v acc_o[4][4];
#pragma unroll
  for (int i = 0; i < 4; ++i)
#pragma unroll
    for (int j = 0; j < 4; ++j) acc_o[i][j] = zero4;
  float lsum[4] = {0.f, 0.f, 0.f, 0.f};

  // stage tile (64 keys) into buffer buf: 4 waves x 2 issues x 8 rows
#define STAGE(buf, kt0_)                                                        \
  {                                                                             \
    _Pragma("unroll")                                                           \
    for (int s = 0; s < 2; ++s) {                                               \
      int rbase = w * 16 + s * 8;                                               \
      int r = rbase + sr;                                                       \
      gld_lds16(&Kg[(size_t)((kt0_) + r) * 64 + ((kbl ^ sr) * 8)],              \
                &Ks[buf][rbase * 64]);                                          \
      gld_lds16(&Vg[(size_t)r * 1024 + (kt0_) + ((kbl ^ sr) * 8)],              \
                &Vs[buf][rbase * 64]);                                          \
    }                                                                           \
  }

  STAGE(0, 0)
  for (int t = 0; t < 16; ++t) {
    const int cur = t & 1;
    __syncthreads();                         // drains prefetch of tile t
    if (t < 15) STAGE(cur ^ 1, (t + 1) * 64)

#pragma unroll
    for (int half = 0; half < 2; ++half) {
      // S-phase + softmax for the two 16-key groups of this half
#pragma unroll
      for (int mh = 0; mh < 2; ++mh) {
        int mt = half * 2 + mh;
        int key = 16 * mt + ln;
        short8v kf0 = *(const short8v*)&Ks[cur][key * 64 + ((qu ^ (key & 7)) * 8)];
        short8v kf1 = *(const short8v*)&Ks[cur][key * 64 + (((4 + qu) ^ (key & 7)) * 8)];
#pragma unroll
        for (int nt = 0; nt < 4; ++nt) {
          float4v s4 = MFMA(kf0, qf[nt][0], zero4);
          s4 = MFMA(kf1, qf[nt][1], s4);
          float e0 = __builtin_amdgcn_exp2f(s4[0]);
          float e1 = __builtin_amdgcn_exp2f(s4[1]);
          float e2 = __builtin_amdgcn_exp2f(s4[2]);
          float e3 = __builtin_amdgcn_exp2f(s4[3]);
          lsum[nt] += (e0 + e1) + (e2 + e3);
          uint2v u;
          u[0] = pack2r(e0, e1);
          u[1] = pack2r(e2, e3);
          *(uint2v*)&Ps[w][(nt * 16 + ln) * 36 + 16 * mh + 4 * qu] = u;
        }
      }
      // PV-phase for this half: O^T[d][q] += V^T · P^T
      short8v pf[4];
#pragma unroll
      for (int nt = 0; nt < 4; ++nt)
        pf[nt] = *(const short8v*)&Ps[w][(nt * 16 + ln) * 36 + qu * 8];
#pragma unroll
      for (int mtv = 0; mtv < 4; ++mtv) {
        int dd = 16 * mtv + ln;
        short8v vf = *(const short8v*)&Vs[cur][dd * 64 + (((half * 4 + qu) ^ (dd & 7)) * 8)];
#pragma unroll
        for (int nt = 0; nt < 4; ++nt)
          acc_o[mtv][nt] = MFMA(vf, pf[nt], acc_o[mtv][nt]);
      }
    }
  }
#undef STAGE

  float inv[4];
#pragma unroll
  for (int nt = 0; nt < 4; ++nt) {
    float tt = lsum[nt];
    tt += __shfl_xor(tt, 16);
    tt += __shfl_xor(tt, 32);
    inv[nt] = 1.0f / tt;
  }
  unsigned short* Og = attnb + (size_t)((co * 8 + b)) * NCK * EMB + h * HD;
#pragma unroll
  for (int mtv = 0; mtv < 4; ++mtv) {
    int dd0 = 16 * mtv + 4 * qu;
#pragma unroll
    for (int nt = 0; nt < 4; ++nt) {
      int q_glob = q0 + w * 64 + nt * 16 + ln;
      ushort4v p;
#pragma unroll
      for (int r = 0; r < 4; ++r) p[r] = f2b(acc_o[mtv][nt][r] * inv[nt]);
      *(ushort4v*)&Og[(size_t)q_glob * EMB + dd0] = p;
    }
  }
}

// ---------------- Output projection (unchanged) ----------------
__global__ __launch_bounds__(256) void proj_gemm(
    const unsigned short* __restrict__ attnb,
    const unsigned short* __restrict__ Wpb, const float* __restrict__ bp,
    float* __restrict__ out)
{
  const int tid = threadIdx.x;
  const int w = tid >> 6, l = tid & 63;
  const int ln = l & 15, qu = l >> 4;
  const int sr = l >> 3, kbl = l & 7;
  const int row0 = blockIdx.x * 128;          // [c][b][n] rows
  const int col0 = blockIdx.y * 128;
  const int c = row0 >> 13;
  const int bglob = (row0 >> 10) & 7;
  const int n0 = row0 & 1023;
  const unsigned short* W = Wpb + c * EMB * EMB;
  const float* bias = bp + c * EMB;

  __shared__ unsigned short As[128 * 64];
  __shared__ unsigned short Bs[128 * 64];

  const int xo = (w & 1) * 64, fo = (w >> 1) * 64;

  float4v acc[4][4];
#pragma unroll
  for (int i = 0; i < 4; ++i)
#pragma unroll
    for (int j = 0; j < 4; ++j) acc[i][j] = (float4v){0.f, 0.f, 0.f, 0.f};

  for (int k0 = 0; k0 < EMB; k0 += 64) {
    __syncthreads();
#pragma unroll
    for (int s = 0; s < 4; ++s) {
      int rbase = w * 32 + s * 8;
      int r = rbase + sr;
      int kb_g = kbl ^ sr;
      gld_lds16(&attnb[(size_t)(row0 + r) * EMB + k0 + kb_g * 8], &As[rbase * 64]);
      gld_lds16(&W    [(size_t)(col0 + r) * EMB + k0 + kb_g * 8], &Bs[rbase * 64]);
    }
    __syncthreads();
#pragma unroll
    for (int ks = 0; ks < 2; ++ks) {
      short8v xf[4], wf[4];
#pragma unroll
      for (int i = 0; i < 4; ++i) {
        int rx = xo + 16 * i + ln;
        xf[i] = *(const short8v*)&As[rx * 64 + (((ks * 4 + qu) ^ (rx & 7)) * 8)];
        int rw = fo + 16 * i + ln;
        wf[i] = *(const short8v*)&Bs[rw * 64 + (((ks * 4 + qu) ^ (rw & 7)) * 8)];
      }
#pragma unroll
      for (int i = 0; i < 4; ++i)
#pragma unroll
        for (int j = 0; j < 4; ++j) acc[i][j] = MFMA(wf[j], xf[i], acc[i][j]);
    }
  }

#pragma unroll
  for (int j = 0; j < 4; ++j) {              // f (M side)
    int f0 = col0 + fo + 16 * j + 4 * qu;    // + r
    float4 b4 = *(const float4*)&bias[f0];
#pragma unroll
    for (int i = 0; i < 4; ++i) {            // token (N side)
      int srow = bglob * SEQ + c * NCK + n0 + xo + 16 * i + ln;
      float4 o;
      o.x = acc[i][j][0] + b4.x;
      o.y = acc[i][j][1] + b4.y;
      o.z = acc[i][j][2] + b4.z;
      o.w = acc[i][j][3] + b4.w;
      *(float4*)&out[(size_t)srow * EMB + f0] = o;
    }
  }
}

extern "C" void kernel_launch(void* const* d_in, const int* in_sizes, int n_in,
                              void* d_out, int out_size, void* d_ws, size_t ws_size,
                              hipStream_t stream) {
  (void)in_sizes; (void)n_in; (void)out_size; (void)ws_size;
  const float* x  = (const float*)d_in[0];
  const float* Wq = (const float*)d_in[1];
  const float* bq = (const float*)d_in[2];
  const float* Wk = (const float*)d_in[3];
  const float* bk = (const float*)d_in[4];
  const float* Wv = (const float*)d_in[5];
  const float* bv = (const float*)d_in[6];
  const float* Wp = (const float*)d_in[7];
  const float* bp = (const float*)d_in[8];
  float* out = (float*)d_out;

  // workspace layout (bf16 elems): [Wb 4*WELEMS][qt][kt][vt][attn(=x_bf)]
  // = 6.3 MB + 4*25.2 MB = 107 MB. x_bf aliases the attn slot: x_bf is only
  // read by qkv_gemm, which completes before attn_kernel writes attnb.
  unsigned short* Wb   = (unsigned short*)d_ws;
  unsigned short* qt   = Wb + 4 * (size_t)WELEMS;
  unsigned short* kt   = qt + QKV_ELEMS;
  unsigned short* vt   = kt + QKV_ELEMS;
  unsigned short* attn = vt + QKV_ELEMS;
  unsigned short* xbf  = attn;  // alias (see above)

  conv_all<<<XBLK + 4 * WBLK, 256, 0, stream>>>(x, Wq, Wk, Wv, Wp, xbf, Wb);
  qkv_gemm<<<dim3(MTOT / 128, EMB / 128, 3), 256, 0, stream>>>(
      xbf, Wb, bq, bk, bv, qt, kt, vt);
  attn_kernel<<<(NCK / 256) * CHUNKS * BATCH * NH, 256, 0, stream>>>(qt, kt, vt, attn);
  proj_gemm<<<dim3(MTOT / 128, EMB / 128), 256, 0, stream>>>(attn, Wb + 3 * (size_t)WELEMS, bp, out);
}